// Round 1
// baseline (579.188 us; speedup 1.0000x reference)
//
#include <hip/hip_runtime.h>
#include <hip/hip_bf16.h>
#include <cstdint>
#include <cstddef>

#define NE 8
#define N_TOK 8192
#define D_EMB 1024
#define D_FFN 2048

#define BM 128
#define BN 128
#define BK 32

typedef __attribute__((ext_vector_type(8))) short short8;
typedef __attribute__((ext_vector_type(4))) float f32x4;

__device__ __forceinline__ unsigned short f2bf(float f) {
  union { float f; unsigned int u; } c; c.f = f;
  unsigned int u = c.u;
  unsigned int r = u + 0x7FFFu + ((u >> 16) & 1u);
  return (unsigned short)(r >> 16);
}

__device__ __forceinline__ void gll16(const void* g, void* l) {
  __builtin_amdgcn_global_load_lds((const __attribute__((address_space(1))) void*)g,
                                   (__attribute__((address_space(3))) void*)l, 16, 0, 0);
}

// ---------------- router: fp32 logits, softmax top-2, renorm gates ----------
__global__ __launch_bounds__(256) void router_k(const float* __restrict__ x,
                                                const float* __restrict__ rw,
                                                int* __restrict__ counts,
                                                int* __restrict__ ti,
                                                float* __restrict__ tg) {
  int w = threadIdx.x >> 6, lane = threadIdx.x & 63;
  int n = blockIdx.x * 4 + w;
  const float4* x4 = (const float4*)(x + (size_t)n * D_EMB);
  const float4* r4 = (const float4*)rw;
  float acc[NE];
#pragma unroll
  for (int e = 0; e < NE; ++e) acc[e] = 0.f;
#pragma unroll
  for (int c = 0; c < 4; ++c) {
    float4 xv = x4[c * 64 + lane];
#pragma unroll
    for (int e = 0; e < NE; ++e) {
      float4 wv = r4[e * 256 + c * 64 + lane];
      acc[e] += xv.x * wv.x + xv.y * wv.y + xv.z * wv.z + xv.w * wv.w;
    }
  }
#pragma unroll
  for (int e = 0; e < NE; ++e) {
    float v = acc[e];
#pragma unroll
    for (int off = 32; off >= 1; off >>= 1) v += __shfl_xor(v, off);
    acc[e] = v;
  }
  if (lane == 0) {
    int e0 = 0; float v0 = acc[0];
#pragma unroll
    for (int e = 1; e < NE; ++e) if (acc[e] > v0) { v0 = acc[e]; e0 = e; }
    int e1 = -1; float v1 = -1e30f;
#pragma unroll
    for (int e = 0; e < NE; ++e) if (e != e0 && acc[e] > v1) { v1 = acc[e]; e1 = e; }
    float p1 = expf(v1 - v0);          // p(top2)/p(top1)
    float g0 = 1.f / (1.f + p1);
    float g1 = p1 * g0;
    ti[2 * n] = e0; ti[2 * n + 1] = e1;
    tg[2 * n] = g0; tg[2 * n + 1] = g1;
    atomicAdd(&counts[e0], 1);
    atomicAdd(&counts[e1], 1);
  }
}

__global__ void prefix_k(const int* __restrict__ counts, int* __restrict__ bases,
                         int* __restrict__ cursor) {
  if (threadIdx.x == 0) {
    int s = 0;
    for (int e = 0; e < NE; ++e) { bases[e] = s; cursor[e] = s; s += counts[e]; }
  }
}

__global__ __launch_bounds__(256) void scatter_k(const int* __restrict__ ti,
                                                 const float* __restrict__ tg,
                                                 int* __restrict__ cursor,
                                                 int* __restrict__ tok,
                                                 float* __restrict__ gate) {
  int n = blockIdx.x * 256 + threadIdx.x;
  if (n >= N_TOK) return;
#pragma unroll
  for (int k = 0; k < 2; ++k) {
    int e = ti[2 * n + k];
    int p = atomicAdd(&cursor[e], 1);
    tok[p] = n;
    gate[p] = tg[2 * n + k];
  }
}

// ---------------- converts ----------------
__global__ __launch_bounds__(256) void cvt_x_k(const float* __restrict__ x,
                                               ushort* __restrict__ xb) {
  const int total = N_TOK * D_EMB / 4;
  for (int i = blockIdx.x * 256 + threadIdx.x; i < total; i += gridDim.x * 256) {
    float4 v = ((const float4*)x)[i];
    ushort4 o;
    o.x = f2bf(v.x); o.y = f2bf(v.y); o.z = f2bf(v.z); o.w = f2bf(v.w);
    ((ushort4*)xb)[i] = o;
  }
}

// transpose src[R][C] fp32 -> dst[C][R] bf16
__global__ __launch_bounds__(256) void transpose_bf_k(const float* __restrict__ src,
                                                      ushort* __restrict__ dst,
                                                      int R, int C) {
  __shared__ ushort t[32][33];
  int bx = blockIdx.x, by = blockIdx.y;
  int rl = threadIdx.x >> 3, q = threadIdx.x & 7;
  float4 v = *(const float4*)&src[(size_t)(by * 32 + rl) * C + bx * 32 + q * 4];
  t[rl][q * 4 + 0] = f2bf(v.x);
  t[rl][q * 4 + 1] = f2bf(v.y);
  t[rl][q * 4 + 2] = f2bf(v.z);
  t[rl][q * 4 + 3] = f2bf(v.w);
  __syncthreads();
  ushort4 o;
  o.x = t[q * 4 + 0][rl];
  o.y = t[q * 4 + 1][rl];
  o.z = t[q * 4 + 2][rl];
  o.w = t[q * 4 + 3][rl];
  *(ushort4*)&dst[(size_t)(bx * 32 + rl) * R + by * 32 + q * 4] = o;
}

// ---------------- grouped GEMM1: h = gelu(x @ W1_e), gathered rows ----------
__global__ __launch_bounds__(256) void gemm1_k(const ushort* __restrict__ xb,
                                               const ushort* __restrict__ w1t,
                                               const int* __restrict__ counts,
                                               const int* __restrict__ bases,
                                               const int* __restrict__ tok,
                                               ushort* __restrict__ h) {
  int bid = blockIdx.x;
  int e = bid >> 10;            // 64 mt * 16 nt per expert
  int rem = bid & 1023;
  int mt = rem >> 4, nt = rem & 15;
  int count = counts[e];
  if (mt * BM >= count) return;
  int base = bases[e];

  __shared__ ushort Al[BM * BK];
  __shared__ ushort Bl[BN * BK];

  int tid = threadIdx.x;
  int w = tid >> 6, lane = tid & 63;

  const ushort* aptr[2]; const ushort* bptr[2];
  ushort* alds[2]; ushort* blds[2];
#pragma unroll
  for (int j = 0; j < 2; ++j) {
    int rl = w * 32 + j * 16 + (lane >> 2);
    int pr = min(base + mt * BM + rl, base + count - 1);
    int t = tok[pr];
    aptr[j] = xb + (size_t)t * D_EMB + (lane & 3) * 8;
    int c = e * D_FFN + nt * BN + rl;
    bptr[j] = w1t + (size_t)c * D_EMB + (lane & 3) * 8;
    alds[j] = Al + (w * 32 + j * 16) * BK;
    blds[j] = Bl + (w * 32 + j * 16) * BK;
  }

  f32x4 zero = {0.f, 0.f, 0.f, 0.f};
  f32x4 acc[4][4];
#pragma unroll
  for (int i = 0; i < 4; ++i)
#pragma unroll
    for (int j = 0; j < 4; ++j) acc[i][j] = zero;

  int wm = w >> 1, wn = w & 1;
  const int arow = (wm * 64 + (lane & 15)) * BK + (lane >> 4) * 8;
  const int brow = (wn * 64 + (lane & 15)) * BK + (lane >> 4) * 8;

  for (int ks = 0; ks < D_EMB / BK; ++ks) {
    __syncthreads();
#pragma unroll
    for (int j = 0; j < 2; ++j) {
      gll16(aptr[j], alds[j]);
      gll16(bptr[j], blds[j]);
      aptr[j] += BK; bptr[j] += BK;
    }
    __syncthreads();
    short8 a[4], b[4];
#pragma unroll
    for (int i = 0; i < 4; ++i) a[i] = *(const short8*)&Al[arow + i * 16 * BK];
#pragma unroll
    for (int j = 0; j < 4; ++j) b[j] = *(const short8*)&Bl[brow + j * 16 * BK];
#pragma unroll
    for (int i = 0; i < 4; ++i)
#pragma unroll
      for (int j = 0; j < 4; ++j)
        acc[i][j] = __builtin_amdgcn_mfma_f32_16x16x32_bf16(a[i], b[j], acc[i][j], 0, 0, 0);
  }

  int r0 = mt * BM + wm * 64, c0 = nt * BN + wn * 64;
#pragma unroll
  for (int i = 0; i < 4; ++i) {
#pragma unroll
    for (int q = 0; q < 4; ++q) {
      int row = r0 + i * 16 + (lane >> 4) * 4 + q;
      if (row < count) {
        size_t hb = (size_t)(base + row) * D_FFN;
#pragma unroll
        for (int j = 0; j < 4; ++j) {
          float v = acc[i][j][q];
          v = 0.5f * v * (1.f + erff(v * 0.70710678118654752f));
          h[hb + c0 + j * 16 + (lane & 15)] = f2bf(v);
        }
      }
    }
  }
}

// ---------------- grouped GEMM2: out[tok] += gate * (h @ W2_e) --------------
__global__ __launch_bounds__(256) void gemm2_k(const ushort* __restrict__ h,
                                               const ushort* __restrict__ w2t,
                                               const int* __restrict__ counts,
                                               const int* __restrict__ bases,
                                               const int* __restrict__ tok,
                                               const float* __restrict__ gate,
                                               float* __restrict__ out) {
  int bid = blockIdx.x;
  int e = bid >> 9;             // 64 mt * 8 nt per expert
  int rem = bid & 511;
  int mt = rem >> 3, nt = rem & 7;
  int count = counts[e];
  if (mt * BM >= count) return;
  int base = bases[e];

  __shared__ ushort Al[BM * BK];
  __shared__ ushort Bl[BN * BK];

  int tid = threadIdx.x;
  int w = tid >> 6, lane = tid & 63;

  const ushort* aptr[2]; const ushort* bptr[2];
  ushort* alds[2]; ushort* blds[2];
#pragma unroll
  for (int j = 0; j < 2; ++j) {
    int rl = w * 32 + j * 16 + (lane >> 2);
    int pr = min(base + mt * BM + rl, base + count - 1);
    aptr[j] = h + (size_t)pr * D_FFN + (lane & 3) * 8;
    int d = nt * BN + rl;       // output column (embedding dim)
    bptr[j] = w2t + (size_t)d * (NE * D_FFN) + e * D_FFN + (lane & 3) * 8;
    alds[j] = Al + (w * 32 + j * 16) * BK;
    blds[j] = Bl + (w * 32 + j * 16) * BK;
  }

  f32x4 zero = {0.f, 0.f, 0.f, 0.f};
  f32x4 acc[4][4];
#pragma unroll
  for (int i = 0; i < 4; ++i)
#pragma unroll
    for (int j = 0; j < 4; ++j) acc[i][j] = zero;

  int wm = w >> 1, wn = w & 1;
  const int arow = (wm * 64 + (lane & 15)) * BK + (lane >> 4) * 8;
  const int brow = (wn * 64 + (lane & 15)) * BK + (lane >> 4) * 8;

  for (int ks = 0; ks < D_FFN / BK; ++ks) {
    __syncthreads();
#pragma unroll
    for (int j = 0; j < 2; ++j) {
      gll16(aptr[j], alds[j]);
      gll16(bptr[j], blds[j]);
      aptr[j] += BK; bptr[j] += BK;
    }
    __syncthreads();
    short8 a[4], b[4];
#pragma unroll
    for (int i = 0; i < 4; ++i) a[i] = *(const short8*)&Al[arow + i * 16 * BK];
#pragma unroll
    for (int j = 0; j < 4; ++j) b[j] = *(const short8*)&Bl[brow + j * 16 * BK];
#pragma unroll
    for (int i = 0; i < 4; ++i)
#pragma unroll
      for (int j = 0; j < 4; ++j)
        acc[i][j] = __builtin_amdgcn_mfma_f32_16x16x32_bf16(a[i], b[j], acc[i][j], 0, 0, 0);
  }

  int r0 = mt * BM + wm * 64, c0 = nt * BN + wn * 64;
#pragma unroll
  for (int i = 0; i < 4; ++i) {
#pragma unroll
    for (int q = 0; q < 4; ++q) {
      int row = r0 + i * 16 + (lane >> 4) * 4 + q;
      if (row < count) {
        int pr = base + row;
        int t = tok[pr];
        float g = gate[pr];
        size_t ob = (size_t)t * D_EMB;
#pragma unroll
        for (int j = 0; j < 4; ++j) {
          atomicAdd(&out[ob + c0 + j * 16 + (lane & 15)], g * acc[i][j][q]);
        }
      }
    }
  }
}

extern "C" void kernel_launch(void* const* d_in, const int* in_sizes, int n_in,
                              void* d_out, int out_size, void* d_ws, size_t ws_size,
                              hipStream_t stream) {
  const float* x  = (const float*)d_in[0];
  const float* rw = (const float*)d_in[1];
  const float* w1 = (const float*)d_in[2];
  const float* w2 = (const float*)d_in[3];
  float* out = (float*)d_out;

  char* ws = (char*)d_ws;
  size_t off = 0;
  auto alloc = [&](size_t bytes) {
    void* p = ws + off;
    off = (off + bytes + 255) & ~(size_t)255;
    return p;
  };
  int*    counts = (int*)alloc(32);
  int*    bases  = (int*)alloc(32);
  int*    cursor = (int*)alloc(32);
  int*    ti     = (int*)alloc((size_t)N_TOK * 2 * sizeof(int));
  float*  tg     = (float*)alloc((size_t)N_TOK * 2 * sizeof(float));
  int*    tok    = (int*)alloc((size_t)N_TOK * 2 * sizeof(int));
  float*  gate   = (float*)alloc((size_t)N_TOK * 2 * sizeof(float));
  ushort* xb     = (ushort*)alloc((size_t)N_TOK * D_EMB * 2);
  ushort* w1t    = (ushort*)alloc((size_t)D_EMB * NE * D_FFN * 2);
  ushort* w2t    = (ushort*)alloc((size_t)D_EMB * NE * D_FFN * 2);
  ushort* hbuf   = (ushort*)alloc((size_t)N_TOK * 2 * D_FFN * 2);
  (void)ws_size; (void)in_sizes; (void)n_in;

  hipMemsetAsync(counts, 0, 32, stream);
  hipMemsetAsync(d_out, 0, (size_t)out_size * sizeof(float), stream);

  cvt_x_k<<<2048, 256, 0, stream>>>(x, xb);
  transpose_bf_k<<<dim3(512, 32), 256, 0, stream>>>(w1, w1t, D_EMB, NE * D_FFN);
  transpose_bf_k<<<dim3(32, 512), 256, 0, stream>>>(w2, w2t, NE * D_FFN, D_EMB);
  router_k<<<N_TOK / 4, 256, 0, stream>>>(x, rw, counts, ti, tg);
  prefix_k<<<1, 64, 0, stream>>>(counts, bases, cursor);
  scatter_k<<<N_TOK / 256, 256, 0, stream>>>(ti, tg, cursor, tok, gate);
  gemm1_k<<<NE * 64 * 16, 256, 0, stream>>>(xb, w1t, counts, bases, tok, hbuf);
  gemm2_k<<<NE * 64 * 8, 256, 0, stream>>>(hbuf, w2t, counts, bases, tok, gate, out);
}

// Round 2
// 336.368 us; speedup vs baseline: 1.7219x; 1.7219x over previous
//
#include <hip/hip_runtime.h>
#include <hip/hip_bf16.h>
#include <cstdint>
#include <cstddef>

#define NE 8
#define N_TOK 8192
#define D_EMB 1024
#define D_FFN 2048

#define BM 128
#define BN 128
#define BK 32

typedef __attribute__((ext_vector_type(8))) short short8;
typedef __attribute__((ext_vector_type(4))) float f32x4;

__device__ __forceinline__ unsigned short f2bf(float f) {
  union { float f; unsigned int u; } c; c.f = f;
  unsigned int u = c.u;
  unsigned int r = u + 0x7FFFu + ((u >> 16) & 1u);
  return (unsigned short)(r >> 16);
}

__device__ __forceinline__ void gll16(const void* g, void* l) {
  __builtin_amdgcn_global_load_lds((const __attribute__((address_space(1))) void*)g,
                                   (__attribute__((address_space(3))) void*)l, 16, 0, 0);
}

// ---- router: fp32 logits, top-2 + renorm gates; fused x->bf16 convert ------
// No atomics here (they cost 180us last round: 16K contended atomics on one
// cacheline). Counts are built by hist_k with block-local aggregation.
__global__ __launch_bounds__(256) void router_k(const float* __restrict__ x,
                                                const float* __restrict__ rw,
                                                int* __restrict__ ti,
                                                float* __restrict__ tg,
                                                ushort* __restrict__ xb) {
  int w = threadIdx.x >> 6, lane = threadIdx.x & 63;
  int n = blockIdx.x * 4 + w;
  const float4* x4 = (const float4*)(x + (size_t)n * D_EMB);
  ushort4* xb4 = (ushort4*)(xb + (size_t)n * D_EMB);
  const float4* r4 = (const float4*)rw;
  float acc[NE];
#pragma unroll
  for (int e = 0; e < NE; ++e) acc[e] = 0.f;
#pragma unroll
  for (int c = 0; c < 4; ++c) {
    float4 xv = x4[c * 64 + lane];
    ushort4 o;
    o.x = f2bf(xv.x); o.y = f2bf(xv.y); o.z = f2bf(xv.z); o.w = f2bf(xv.w);
    xb4[c * 64 + lane] = o;
#pragma unroll
    for (int e = 0; e < NE; ++e) {
      float4 wv = r4[e * 256 + c * 64 + lane];
      acc[e] += xv.x * wv.x + xv.y * wv.y + xv.z * wv.z + xv.w * wv.w;
    }
  }
#pragma unroll
  for (int e = 0; e < NE; ++e) {
    float v = acc[e];
#pragma unroll
    for (int off = 32; off >= 1; off >>= 1) v += __shfl_xor(v, off);
    acc[e] = v;
  }
  if (lane == 0) {
    int e0 = 0; float v0 = acc[0];
#pragma unroll
    for (int e = 1; e < NE; ++e) if (acc[e] > v0) { v0 = acc[e]; e0 = e; }
    int e1 = -1; float v1 = -1e30f;
#pragma unroll
    for (int e = 0; e < NE; ++e) if (e != e0 && acc[e] > v1) { v1 = acc[e]; e1 = e; }
    float p1 = expf(v1 - v0);          // p(top2)/p(top1)
    float g0 = 1.f / (1.f + p1);
    float g1 = p1 * g0;
    ti[2 * n] = e0; ti[2 * n + 1] = e1;
    tg[2 * n] = g0; tg[2 * n + 1] = g1;
  }
}

// ---- counts: LDS-aggregated histogram, 8 global atomics per block ----------
__global__ __launch_bounds__(256) void hist_k(const int* __restrict__ ti,
                                              int* __restrict__ counts) {
  __shared__ int lc[NE];
  if (threadIdx.x < NE) lc[threadIdx.x] = 0;
  __syncthreads();
  int s = blockIdx.x * 512 + threadIdx.x;
  atomicAdd(&lc[ti[s]], 1);
  atomicAdd(&lc[ti[s + 256]], 1);
  __syncthreads();
  if (threadIdx.x < NE) atomicAdd(&counts[threadIdx.x], lc[threadIdx.x]);
}

__global__ void prefix_k(const int* __restrict__ counts, int* __restrict__ bases,
                         int* __restrict__ cursor) {
  if (threadIdx.x == 0) {
    int s = 0;
    for (int e = 0; e < NE; ++e) { bases[e] = s; cursor[e] = s; s += counts[e]; }
  }
}

// ---- scatter: two-phase (LDS-local offset + one cursor atomic per expert) --
__global__ __launch_bounds__(256) void scatter_k(const int* __restrict__ ti,
                                                 const float* __restrict__ tg,
                                                 int* __restrict__ cursor,
                                                 int* __restrict__ tok,
                                                 float* __restrict__ gate) {
  __shared__ int lc[NE], lb[NE];
  if (threadIdx.x < NE) lc[threadIdx.x] = 0;
  __syncthreads();
  int s = blockIdx.x * 256 + threadIdx.x;
  int e = ti[s];
  float g = tg[s];
  int loc = atomicAdd(&lc[e], 1);
  __syncthreads();
  if (threadIdx.x < NE) lb[threadIdx.x] = atomicAdd(&cursor[threadIdx.x], lc[threadIdx.x]);
  __syncthreads();
  int pos = lb[e] + loc;
  tok[pos] = s >> 1;
  gate[pos] = g;
}

// transpose src[R][C] fp32 -> dst[C][R] bf16
__global__ __launch_bounds__(256) void transpose_bf_k(const float* __restrict__ src,
                                                      ushort* __restrict__ dst,
                                                      int R, int C) {
  __shared__ ushort t[32][33];
  int bx = blockIdx.x, by = blockIdx.y;
  int rl = threadIdx.x >> 3, q = threadIdx.x & 7;
  float4 v = *(const float4*)&src[(size_t)(by * 32 + rl) * C + bx * 32 + q * 4];
  t[rl][q * 4 + 0] = f2bf(v.x);
  t[rl][q * 4 + 1] = f2bf(v.y);
  t[rl][q * 4 + 2] = f2bf(v.z);
  t[rl][q * 4 + 3] = f2bf(v.w);
  __syncthreads();
  ushort4 o;
  o.x = t[q * 4 + 0][rl];
  o.y = t[q * 4 + 1][rl];
  o.z = t[q * 4 + 2][rl];
  o.w = t[q * 4 + 3][rl];
  *(ushort4*)&dst[(size_t)(bx * 32 + rl) * R + by * 32 + q * 4] = o;
}

// ---------------- grouped GEMM1: h = gelu(x @ W1_e), gathered rows ----------
__global__ __launch_bounds__(256) void gemm1_k(const ushort* __restrict__ xb,
                                               const ushort* __restrict__ w1t,
                                               const int* __restrict__ counts,
                                               const int* __restrict__ bases,
                                               const int* __restrict__ tok,
                                               ushort* __restrict__ h) {
  int bid = blockIdx.x;
  int e = bid >> 10;            // 64 mt * 16 nt per expert
  int rem = bid & 1023;
  int mt = rem >> 4, nt = rem & 15;
  int count = counts[e];
  if (mt * BM >= count) return;
  int base = bases[e];

  __shared__ ushort Al[BM * BK];
  __shared__ ushort Bl[BN * BK];

  int tid = threadIdx.x;
  int w = tid >> 6, lane = tid & 63;

  const ushort* aptr[2]; const ushort* bptr[2];
  ushort* alds[2]; ushort* blds[2];
#pragma unroll
  for (int j = 0; j < 2; ++j) {
    int rl = w * 32 + j * 16 + (lane >> 2);
    int pr = min(base + mt * BM + rl, base + count - 1);
    int t = tok[pr];
    aptr[j] = xb + (size_t)t * D_EMB + (lane & 3) * 8;
    int c = e * D_FFN + nt * BN + rl;
    bptr[j] = w1t + (size_t)c * D_EMB + (lane & 3) * 8;
    alds[j] = Al + (w * 32 + j * 16) * BK;
    blds[j] = Bl + (w * 32 + j * 16) * BK;
  }

  f32x4 zero = {0.f, 0.f, 0.f, 0.f};
  f32x4 acc[4][4];
#pragma unroll
  for (int i = 0; i < 4; ++i)
#pragma unroll
    for (int j = 0; j < 4; ++j) acc[i][j] = zero;

  int wm = w >> 1, wn = w & 1;
  const int arow = (wm * 64 + (lane & 15)) * BK + (lane >> 4) * 8;
  const int brow = (wn * 64 + (lane & 15)) * BK + (lane >> 4) * 8;

  for (int ks = 0; ks < D_EMB / BK; ++ks) {
    __syncthreads();
#pragma unroll
    for (int j = 0; j < 2; ++j) {
      gll16(aptr[j], alds[j]);
      gll16(bptr[j], blds[j]);
      aptr[j] += BK; bptr[j] += BK;
    }
    __syncthreads();
    short8 a[4], b[4];
#pragma unroll
    for (int i = 0; i < 4; ++i) a[i] = *(const short8*)&Al[arow + i * 16 * BK];
#pragma unroll
    for (int j = 0; j < 4; ++j) b[j] = *(const short8*)&Bl[brow + j * 16 * BK];
#pragma unroll
    for (int i = 0; i < 4; ++i)
#pragma unroll
      for (int j = 0; j < 4; ++j)
        acc[i][j] = __builtin_amdgcn_mfma_f32_16x16x32_bf16(a[i], b[j], acc[i][j], 0, 0, 0);
  }

  int r0 = mt * BM + wm * 64, c0 = nt * BN + wn * 64;
#pragma unroll
  for (int i = 0; i < 4; ++i) {
#pragma unroll
    for (int q = 0; q < 4; ++q) {
      int row = r0 + i * 16 + (lane >> 4) * 4 + q;
      if (row < count) {
        size_t hb = (size_t)(base + row) * D_FFN;
#pragma unroll
        for (int j = 0; j < 4; ++j) {
          float v = acc[i][j][q];
          v = 0.5f * v * (1.f + erff(v * 0.70710678118654752f));
          h[hb + c0 + j * 16 + (lane & 15)] = f2bf(v);
        }
      }
    }
  }
}

// ---------------- grouped GEMM2: out[tok] += gate * (h @ W2_e) --------------
__global__ __launch_bounds__(256) void gemm2_k(const ushort* __restrict__ h,
                                               const ushort* __restrict__ w2t,
                                               const int* __restrict__ counts,
                                               const int* __restrict__ bases,
                                               const int* __restrict__ tok,
                                               const float* __restrict__ gate,
                                               float* __restrict__ out) {
  int bid = blockIdx.x;
  int e = bid >> 9;             // 64 mt * 8 nt per expert
  int rem = bid & 511;
  int mt = rem >> 3, nt = rem & 7;
  int count = counts[e];
  if (mt * BM >= count) return;
  int base = bases[e];

  __shared__ ushort Al[BM * BK];
  __shared__ ushort Bl[BN * BK];

  int tid = threadIdx.x;
  int w = tid >> 6, lane = tid & 63;

  const ushort* aptr[2]; const ushort* bptr[2];
  ushort* alds[2]; ushort* blds[2];
#pragma unroll
  for (int j = 0; j < 2; ++j) {
    int rl = w * 32 + j * 16 + (lane >> 2);
    int pr = min(base + mt * BM + rl, base + count - 1);
    aptr[j] = h + (size_t)pr * D_FFN + (lane & 3) * 8;
    int d = nt * BN + rl;       // output column (embedding dim)
    bptr[j] = w2t + (size_t)d * (NE * D_FFN) + e * D_FFN + (lane & 3) * 8;
    alds[j] = Al + (w * 32 + j * 16) * BK;
    blds[j] = Bl + (w * 32 + j * 16) * BK;
  }

  f32x4 zero = {0.f, 0.f, 0.f, 0.f};
  f32x4 acc[4][4];
#pragma unroll
  for (int i = 0; i < 4; ++i)
#pragma unroll
    for (int j = 0; j < 4; ++j) acc[i][j] = zero;

  int wm = w >> 1, wn = w & 1;
  const int arow = (wm * 64 + (lane & 15)) * BK + (lane >> 4) * 8;
  const int brow = (wn * 64 + (lane & 15)) * BK + (lane >> 4) * 8;

  for (int ks = 0; ks < D_FFN / BK; ++ks) {
    __syncthreads();
#pragma unroll
    for (int j = 0; j < 2; ++j) {
      gll16(aptr[j], alds[j]);
      gll16(bptr[j], blds[j]);
      aptr[j] += BK; bptr[j] += BK;
    }
    __syncthreads();
    short8 a[4], b[4];
#pragma unroll
    for (int i = 0; i < 4; ++i) a[i] = *(const short8*)&Al[arow + i * 16 * BK];
#pragma unroll
    for (int j = 0; j < 4; ++j) b[j] = *(const short8*)&Bl[brow + j * 16 * BK];
#pragma unroll
    for (int i = 0; i < 4; ++i)
#pragma unroll
      for (int j = 0; j < 4; ++j)
        acc[i][j] = __builtin_amdgcn_mfma_f32_16x16x32_bf16(a[i], b[j], acc[i][j], 0, 0, 0);
  }

  int r0 = mt * BM + wm * 64, c0 = nt * BN + wn * 64;
#pragma unroll
  for (int i = 0; i < 4; ++i) {
#pragma unroll
    for (int q = 0; q < 4; ++q) {
      int row = r0 + i * 16 + (lane >> 4) * 4 + q;
      if (row < count) {
        int pr = base + row;
        int t = tok[pr];
        float g = gate[pr];
        size_t ob = (size_t)t * D_EMB;
#pragma unroll
        for (int j = 0; j < 4; ++j) {
          atomicAdd(&out[ob + c0 + j * 16 + (lane & 15)], g * acc[i][j][q]);
        }
      }
    }
  }
}

extern "C" void kernel_launch(void* const* d_in, const int* in_sizes, int n_in,
                              void* d_out, int out_size, void* d_ws, size_t ws_size,
                              hipStream_t stream) {
  const float* x  = (const float*)d_in[0];
  const float* rw = (const float*)d_in[1];
  const float* w1 = (const float*)d_in[2];
  const float* w2 = (const float*)d_in[3];
  float* out = (float*)d_out;

  char* ws = (char*)d_ws;
  size_t off = 0;
  auto alloc = [&](size_t bytes) {
    void* p = ws + off;
    off = (off + bytes + 255) & ~(size_t)255;
    return p;
  };
  int*    counts = (int*)alloc(32);
  int*    bases  = (int*)alloc(32);
  int*    cursor = (int*)alloc(32);
  int*    ti     = (int*)alloc((size_t)N_TOK * 2 * sizeof(int));
  float*  tg     = (float*)alloc((size_t)N_TOK * 2 * sizeof(float));
  int*    tok    = (int*)alloc((size_t)N_TOK * 2 * sizeof(int));
  float*  gate   = (float*)alloc((size_t)N_TOK * 2 * sizeof(float));
  ushort* xb     = (ushort*)alloc((size_t)N_TOK * D_EMB * 2);
  ushort* w1t    = (ushort*)alloc((size_t)D_EMB * NE * D_FFN * 2);
  ushort* w2t    = (ushort*)alloc((size_t)D_EMB * NE * D_FFN * 2);
  ushort* hbuf   = (ushort*)alloc((size_t)N_TOK * 2 * D_FFN * 2);
  (void)ws_size; (void)in_sizes; (void)n_in;

  hipMemsetAsync(counts, 0, 32, stream);
  hipMemsetAsync(d_out, 0, (size_t)out_size * sizeof(float), stream);

  router_k<<<N_TOK / 4, 256, 0, stream>>>(x, rw, ti, tg, xb);
  transpose_bf_k<<<dim3(512, 32), 256, 0, stream>>>(w1, w1t, D_EMB, NE * D_FFN);
  transpose_bf_k<<<dim3(32, 512), 256, 0, stream>>>(w2, w2t, NE * D_FFN, D_EMB);
  hist_k<<<N_TOK * 2 / 512, 256, 0, stream>>>(ti, counts);
  prefix_k<<<1, 64, 0, stream>>>(counts, bases, cursor);
  scatter_k<<<N_TOK * 2 / 256, 256, 0, stream>>>(ti, tg, cursor, tok, gate);
  gemm1_k<<<NE * 64 * 16, 256, 0, stream>>>(xb, w1t, counts, bases, tok, hbuf);
  gemm2_k<<<NE * 64 * 8, 256, 0, stream>>>(hbuf, w2t, counts, bases, tok, gate, out);
}

// Round 3
// 284.630 us; speedup vs baseline: 2.0349x; 1.1818x over previous
//
#include <hip/hip_runtime.h>
#include <hip/hip_bf16.h>
#include <cstdint>
#include <cstddef>

#define NE 8
#define N_TOK 8192
#define D_EMB 1024
#define D_FFN 2048

#define BM 128
#define BN 128
#define BK 32

typedef __attribute__((ext_vector_type(8))) short short8;
typedef __attribute__((ext_vector_type(4))) float f32x4;

__device__ __forceinline__ unsigned short f2bf(float f) {
  union { float f; unsigned int u; } c; c.f = f;
  unsigned int u = c.u;
  unsigned int r = u + 0x7FFFu + ((u >> 16) & 1u);
  return (unsigned short)(r >> 16);
}

__device__ __forceinline__ float bf2f(unsigned short u) {
  union { unsigned int u; float f; } c; c.u = ((unsigned int)u) << 16;
  return c.f;
}

__device__ __forceinline__ void gll16(const void* g, void* l) {
  __builtin_amdgcn_global_load_lds((const __attribute__((address_space(1))) void*)g,
                                   (__attribute__((address_space(3))) void*)l, 16, 0, 0);
}

// ---- router: fp32 logits, top-2 + renorm gates; fused x->bf16 convert ------
__global__ __launch_bounds__(256) void router_k(const float* __restrict__ x,
                                                const float* __restrict__ rw,
                                                int* __restrict__ ti,
                                                float* __restrict__ tg,
                                                ushort* __restrict__ xb) {
  int w = threadIdx.x >> 6, lane = threadIdx.x & 63;
  int n = blockIdx.x * 4 + w;
  const float4* x4 = (const float4*)(x + (size_t)n * D_EMB);
  ushort4* xb4 = (ushort4*)(xb + (size_t)n * D_EMB);
  const float4* r4 = (const float4*)rw;
  float acc[NE];
#pragma unroll
  for (int e = 0; e < NE; ++e) acc[e] = 0.f;
#pragma unroll
  for (int c = 0; c < 4; ++c) {
    float4 xv = x4[c * 64 + lane];
    ushort4 o;
    o.x = f2bf(xv.x); o.y = f2bf(xv.y); o.z = f2bf(xv.z); o.w = f2bf(xv.w);
    xb4[c * 64 + lane] = o;
#pragma unroll
    for (int e = 0; e < NE; ++e) {
      float4 wv = r4[e * 256 + c * 64 + lane];
      acc[e] += xv.x * wv.x + xv.y * wv.y + xv.z * wv.z + xv.w * wv.w;
    }
  }
#pragma unroll
  for (int e = 0; e < NE; ++e) {
    float v = acc[e];
#pragma unroll
    for (int off = 32; off >= 1; off >>= 1) v += __shfl_xor(v, off);
    acc[e] = v;
  }
  if (lane == 0) {
    int e0 = 0; float v0 = acc[0];
#pragma unroll
    for (int e = 1; e < NE; ++e) if (acc[e] > v0) { v0 = acc[e]; e0 = e; }
    int e1 = -1; float v1 = -1e30f;
#pragma unroll
    for (int e = 0; e < NE; ++e) if (e != e0 && acc[e] > v1) { v1 = acc[e]; e1 = e; }
    float p1 = expf(v1 - v0);          // p(top2)/p(top1)
    float g0 = 1.f / (1.f + p1);
    float g1 = p1 * g0;
    ti[2 * n] = e0; ti[2 * n + 1] = e1;
    tg[2 * n] = g0; tg[2 * n + 1] = g1;
  }
}

// ---- counts: LDS-aggregated histogram, 8 global atomics per block ----------
__global__ __launch_bounds__(256) void hist_k(const int* __restrict__ ti,
                                              int* __restrict__ counts) {
  __shared__ int lc[NE];
  if (threadIdx.x < NE) lc[threadIdx.x] = 0;
  __syncthreads();
  int s = blockIdx.x * 512 + threadIdx.x;
  atomicAdd(&lc[ti[s]], 1);
  atomicAdd(&lc[ti[s + 256]], 1);
  __syncthreads();
  if (threadIdx.x < NE) atomicAdd(&counts[threadIdx.x], lc[threadIdx.x]);
}

__global__ void prefix_k(const int* __restrict__ counts, int* __restrict__ bases,
                         int* __restrict__ cursor) {
  if (threadIdx.x == 0) {
    int s = 0;
    for (int e = 0; e < NE; ++e) { bases[e] = s; cursor[e] = s; s += counts[e]; }
  }
}

// ---- scatter: two-phase; also records inv[s] = slot for combine ------------
__global__ __launch_bounds__(256) void scatter_k(const int* __restrict__ ti,
                                                 const float* __restrict__ tg,
                                                 int* __restrict__ cursor,
                                                 int* __restrict__ tok,
                                                 float* __restrict__ gate,
                                                 int* __restrict__ inv) {
  __shared__ int lc[NE], lb[NE];
  if (threadIdx.x < NE) lc[threadIdx.x] = 0;
  __syncthreads();
  int s = blockIdx.x * 256 + threadIdx.x;
  int e = ti[s];
  float g = tg[s];
  int loc = atomicAdd(&lc[e], 1);
  __syncthreads();
  if (threadIdx.x < NE) lb[threadIdx.x] = atomicAdd(&cursor[threadIdx.x], lc[threadIdx.x]);
  __syncthreads();
  int pos = lb[e] + loc;
  tok[pos] = s >> 1;
  gate[pos] = g;
  inv[s] = pos;
}

// transpose src[R][C] fp32 -> dst[C][R] bf16
__global__ __launch_bounds__(256) void transpose_bf_k(const float* __restrict__ src,
                                                      ushort* __restrict__ dst,
                                                      int R, int C) {
  __shared__ ushort t[32][33];
  int bx = blockIdx.x, by = blockIdx.y;
  int rl = threadIdx.x >> 3, q = threadIdx.x & 7;
  float4 v = *(const float4*)&src[(size_t)(by * 32 + rl) * C + bx * 32 + q * 4];
  t[rl][q * 4 + 0] = f2bf(v.x);
  t[rl][q * 4 + 1] = f2bf(v.y);
  t[rl][q * 4 + 2] = f2bf(v.z);
  t[rl][q * 4 + 3] = f2bf(v.w);
  __syncthreads();
  ushort4 o;
  o.x = t[q * 4 + 0][rl];
  o.y = t[q * 4 + 1][rl];
  o.z = t[q * 4 + 2][rl];
  o.w = t[q * 4 + 3][rl];
  *(ushort4*)&dst[(size_t)(bx * 32 + rl) * R + by * 32 + q * 4] = o;
}

// LDS slot swizzle: physical slot = logical slot ^ ((row>>1)&3).
// Staged via pre-swizzled GLOBAL source (gll dest must stay linear, rule #21);
// ds_read applies the same XOR. Consecutive 8 lanes then cover all 8 bank-quads.

// ---------------- grouped GEMM1: h = gelu(x @ W1_e), gathered rows ----------
__global__ __launch_bounds__(256) void gemm1_k(const ushort* __restrict__ xb,
                                               const ushort* __restrict__ w1t,
                                               const int* __restrict__ counts,
                                               const int* __restrict__ bases,
                                               const int* __restrict__ tok,
                                               ushort* __restrict__ h) {
  int bid = (int)blockIdx.x;
  bid = (bid & 7) * (NE * 1024 / 8) + (bid >> 3);   // XCD-contiguous: 1 expert/XCD
  int e = bid >> 10;            // 64 mt * 16 nt per expert
  int rem = bid & 1023;
  int mt = rem >> 4, nt = rem & 15;
  int count = counts[e];
  if (mt * BM >= count) return;
  int base = bases[e];

  __shared__ ushort Al[BM * BK];
  __shared__ ushort Bl[BN * BK];

  int tid = threadIdx.x;
  int w = tid >> 6, lane = tid & 63;

  // pre-swizzled source column: slot' = (lane&3) ^ ((lane>>3)&3)  [= (row>>1)&3]
  const int ssw = (((lane & 3) ^ ((lane >> 3) & 3))) * 8;

  const ushort* aptr[2]; const ushort* bptr[2];
  ushort* alds[2]; ushort* blds[2];
#pragma unroll
  for (int j = 0; j < 2; ++j) {
    int rl = w * 32 + j * 16 + (lane >> 2);
    int pr = min(base + mt * BM + rl, base + count - 1);
    int t = tok[pr];
    aptr[j] = xb + (size_t)t * D_EMB + ssw;
    int c = e * D_FFN + nt * BN + rl;
    bptr[j] = w1t + (size_t)c * D_EMB + ssw;
    alds[j] = Al + (w * 32 + j * 16) * BK;
    blds[j] = Bl + (w * 32 + j * 16) * BK;
  }

  f32x4 zero = {0.f, 0.f, 0.f, 0.f};
  f32x4 acc[4][4];
#pragma unroll
  for (int i = 0; i < 4; ++i)
#pragma unroll
    for (int j = 0; j < 4; ++j) acc[i][j] = zero;

  int wm = w >> 1, wn = w & 1;
  // swizzled read: physical slot = (lane>>4) ^ ((row>>1)&3), row low bits = lane&15
  const int rsw = ((lane >> 4) ^ (((lane & 15) >> 1) & 3)) * 8;
  const int arow = (wm * 64 + (lane & 15)) * BK + rsw;
  const int brow = (wn * 64 + (lane & 15)) * BK + rsw;

  for (int ks = 0; ks < D_EMB / BK; ++ks) {
    __syncthreads();
#pragma unroll
    for (int j = 0; j < 2; ++j) {
      gll16(aptr[j], alds[j]);
      gll16(bptr[j], blds[j]);
      aptr[j] += BK; bptr[j] += BK;
    }
    __syncthreads();
    short8 a[4], b[4];
#pragma unroll
    for (int i = 0; i < 4; ++i) a[i] = *(const short8*)&Al[arow + i * 16 * BK];
#pragma unroll
    for (int j = 0; j < 4; ++j) b[j] = *(const short8*)&Bl[brow + j * 16 * BK];
#pragma unroll
    for (int i = 0; i < 4; ++i)
#pragma unroll
      for (int j = 0; j < 4; ++j)
        acc[i][j] = __builtin_amdgcn_mfma_f32_16x16x32_bf16(a[i], b[j], acc[i][j], 0, 0, 0);
  }

  int r0 = mt * BM + wm * 64, c0 = nt * BN + wn * 64;
#pragma unroll
  for (int i = 0; i < 4; ++i) {
#pragma unroll
    for (int q = 0; q < 4; ++q) {
      int row = r0 + i * 16 + (lane >> 4) * 4 + q;
      if (row < count) {
        size_t hb = (size_t)(base + row) * D_FFN;
#pragma unroll
        for (int j = 0; j < 4; ++j) {
          float v = acc[i][j][q];
          v = 0.5f * v * (1.f + erff(v * 0.70710678118654752f));
          h[hb + c0 + j * 16 + (lane & 15)] = f2bf(v);
        }
      }
    }
  }
}

// ------- grouped GEMM2: y[slot] = gate * (h @ W2_e), slot order, bf16 -------
__global__ __launch_bounds__(256) void gemm2_k(const ushort* __restrict__ h,
                                               const ushort* __restrict__ w2t,
                                               const int* __restrict__ counts,
                                               const int* __restrict__ bases,
                                               const int* __restrict__ tok,
                                               const float* __restrict__ gate,
                                               ushort* __restrict__ y) {
  int bid = (int)blockIdx.x;
  bid = (bid & 7) * (NE * 512 / 8) + (bid >> 3);    // XCD-contiguous: 1 expert/XCD
  int e = bid >> 9;             // 64 mt * 8 nt per expert
  int rem = bid & 511;
  int mt = rem >> 3, nt = rem & 7;
  int count = counts[e];
  if (mt * BM >= count) return;
  int base = bases[e];

  __shared__ ushort Al[BM * BK];
  __shared__ ushort Bl[BN * BK];

  int tid = threadIdx.x;
  int w = tid >> 6, lane = tid & 63;

  const int ssw = (((lane & 3) ^ ((lane >> 3) & 3))) * 8;

  const ushort* aptr[2]; const ushort* bptr[2];
  ushort* alds[2]; ushort* blds[2];
#pragma unroll
  for (int j = 0; j < 2; ++j) {
    int rl = w * 32 + j * 16 + (lane >> 2);
    int pr = min(base + mt * BM + rl, base + count - 1);
    aptr[j] = h + (size_t)pr * D_FFN + ssw;
    int d = nt * BN + rl;       // output column (embedding dim)
    bptr[j] = w2t + (size_t)d * (NE * D_FFN) + e * D_FFN + ssw;
    alds[j] = Al + (w * 32 + j * 16) * BK;
    blds[j] = Bl + (w * 32 + j * 16) * BK;
  }

  f32x4 zero = {0.f, 0.f, 0.f, 0.f};
  f32x4 acc[4][4];
#pragma unroll
  for (int i = 0; i < 4; ++i)
#pragma unroll
    for (int j = 0; j < 4; ++j) acc[i][j] = zero;

  int wm = w >> 1, wn = w & 1;
  const int rsw = ((lane >> 4) ^ (((lane & 15) >> 1) & 3)) * 8;
  const int arow = (wm * 64 + (lane & 15)) * BK + rsw;
  const int brow = (wn * 64 + (lane & 15)) * BK + rsw;

  for (int ks = 0; ks < D_FFN / BK; ++ks) {
    __syncthreads();
#pragma unroll
    for (int j = 0; j < 2; ++j) {
      gll16(aptr[j], alds[j]);
      gll16(bptr[j], blds[j]);
      aptr[j] += BK; bptr[j] += BK;
    }
    __syncthreads();
    short8 a[4], b[4];
#pragma unroll
    for (int i = 0; i < 4; ++i) a[i] = *(const short8*)&Al[arow + i * 16 * BK];
#pragma unroll
    for (int j = 0; j < 4; ++j) b[j] = *(const short8*)&Bl[brow + j * 16 * BK];
#pragma unroll
    for (int i = 0; i < 4; ++i)
#pragma unroll
      for (int j = 0; j < 4; ++j)
        acc[i][j] = __builtin_amdgcn_mfma_f32_16x16x32_bf16(a[i], b[j], acc[i][j], 0, 0, 0);
  }

  int r0 = mt * BM + wm * 64, c0 = nt * BN + wn * 64;
#pragma unroll
  for (int i = 0; i < 4; ++i) {
#pragma unroll
    for (int q = 0; q < 4; ++q) {
      int row = r0 + i * 16 + (lane >> 4) * 4 + q;
      if (row < count) {
        int pr = base + row;
        float g = gate[pr];
        size_t yb = (size_t)pr * D_EMB;
#pragma unroll
        for (int j = 0; j < 4; ++j) {
          y[yb + c0 + j * 16 + (lane & 15)] = f2bf(g * acc[i][j][q]);
        }
      }
    }
  }
}

// ---- combine: out[n] = y[inv[2n]] + y[inv[2n+1]] (gates pre-applied) -------
__global__ __launch_bounds__(256) void combine_k(const ushort* __restrict__ y,
                                                 const int* __restrict__ inv,
                                                 float* __restrict__ out) {
  int n = blockIdx.x;
  int p0 = inv[2 * n], p1 = inv[2 * n + 1];
  const ushort4* r0 = (const ushort4*)(y + (size_t)p0 * D_EMB);
  const ushort4* r1 = (const ushort4*)(y + (size_t)p1 * D_EMB);
  float4* o = (float4*)(out + (size_t)n * D_EMB);
  int i = threadIdx.x;
  ushort4 a = r0[i], b = r1[i];
  float4 v;
  v.x = bf2f(a.x) + bf2f(b.x);
  v.y = bf2f(a.y) + bf2f(b.y);
  v.z = bf2f(a.z) + bf2f(b.z);
  v.w = bf2f(a.w) + bf2f(b.w);
  o[i] = v;
}

extern "C" void kernel_launch(void* const* d_in, const int* in_sizes, int n_in,
                              void* d_out, int out_size, void* d_ws, size_t ws_size,
                              hipStream_t stream) {
  const float* x  = (const float*)d_in[0];
  const float* rw = (const float*)d_in[1];
  const float* w1 = (const float*)d_in[2];
  const float* w2 = (const float*)d_in[3];
  float* out = (float*)d_out;

  char* ws = (char*)d_ws;
  size_t off = 0;
  auto alloc = [&](size_t bytes) {
    void* p = ws + off;
    off = (off + bytes + 255) & ~(size_t)255;
    return p;
  };
  int*    counts = (int*)alloc(32);
  int*    bases  = (int*)alloc(32);
  int*    cursor = (int*)alloc(32);
  int*    ti     = (int*)alloc((size_t)N_TOK * 2 * sizeof(int));
  float*  tg     = (float*)alloc((size_t)N_TOK * 2 * sizeof(float));
  int*    tok    = (int*)alloc((size_t)N_TOK * 2 * sizeof(int));
  float*  gate   = (float*)alloc((size_t)N_TOK * 2 * sizeof(float));
  int*    inv    = (int*)alloc((size_t)N_TOK * 2 * sizeof(int));
  ushort* xb     = (ushort*)alloc((size_t)N_TOK * D_EMB * 2);
  ushort* w1t    = (ushort*)alloc((size_t)D_EMB * NE * D_FFN * 2);
  ushort* w2t    = (ushort*)alloc((size_t)D_EMB * NE * D_FFN * 2);
  ushort* hbuf   = (ushort*)alloc((size_t)N_TOK * 2 * D_FFN * 2);
  ushort* ybuf   = (ushort*)alloc((size_t)N_TOK * 2 * D_EMB * 2);
  (void)ws_size; (void)in_sizes; (void)n_in; (void)out_size;

  hipMemsetAsync(counts, 0, 32, stream);

  router_k<<<N_TOK / 4, 256, 0, stream>>>(x, rw, ti, tg, xb);
  transpose_bf_k<<<dim3(512, 32), 256, 0, stream>>>(w1, w1t, D_EMB, NE * D_FFN);
  transpose_bf_k<<<dim3(32, 512), 256, 0, stream>>>(w2, w2t, NE * D_FFN, D_EMB);
  hist_k<<<N_TOK * 2 / 512, 256, 0, stream>>>(ti, counts);
  prefix_k<<<1, 64, 0, stream>>>(counts, bases, cursor);
  scatter_k<<<N_TOK * 2 / 256, 256, 0, stream>>>(ti, tg, cursor, tok, gate, inv);
  gemm1_k<<<NE * 64 * 16, 256, 0, stream>>>(xb, w1t, counts, bases, tok, hbuf);
  gemm2_k<<<NE * 64 * 8, 256, 0, stream>>>(hbuf, w2t, counts, bases, tok, gate, ybuf);
  combine_k<<<N_TOK, 256, 0, stream>>>(ybuf, inv, out);
}